// Round 3
// baseline (375.317 us; speedup 1.0000x reference)
//
#include <hip/hip_runtime.h>
#include <stdint.h>

#define NUM_LEVELS 16
#define LEVEL_DIM 2
#define BASE_RES 16
#define LOG2_T 19
#define TABLE_SIZE (1u << LOG2_T)
#define TABLE_MASK (TABLE_SIZE - 1u)
#define PAIR_MASK (TABLE_MASK & ~1u)   /* 0x7FFFE: 16B-aligned entry pair */

#define CPL 256      // chunk-blocks per level (8*CPL = 2048 = resident-block capacity)
#define BLOCK 256

typedef float v2f __attribute__((ext_vector_type(2)));
typedef float v4f __attribute__((ext_vector_type(4)));

// ---------------- Phase 1: level-sharded gather ----------------
// blockIdx % 8 -> XCD (dispatch round-robin). Levels 0..7 run first
// (blocks 0..2047), then 8..15; each XCD's 4MB L2 holds exactly one table.
//
// Hash-pair trick: hash = ix ^ iy*P2 ^ iz*P3 ^ lv. For EVEN ix,
// hash(ix+1) = hash(ix) ^ 1, so both x-corners sit in the same 16B-aligned
// entry pair -> one dwordx4 load covers two corners (4 line-requests/point
// instead of 8). Odd ix falls back to 8x dwordx2. Avg 6 requests/point.
//
// x loads are NONTEMPORAL on purpose: each XCD's 4MB L2 holds exactly its
// level's 4MB table. Round-1 measured that plain x loads routed 96MB of x
// stream through L2 and evicted ~85MB of table lines (FETCH 164->248MB).
// NT keeps the table L2-resident; x re-reads are served by L3.
__global__ __launch_bounds__(256, 8) void gather_level_kernel(
    const float* __restrict__ x,
    const float* __restrict__ tables,
    float* __restrict__ ws,      // [NUM_LEVELS][N] float2, level-major
    int N)
{
    int g = blockIdx.x;
    int half  = g / (8 * CPL);          // 0 or 1
    int h     = g % (8 * CPL);
    int level = (h & 7) + 8 * half;
    int chunk = h >> 3;
    int P     = (N + CPL - 1) / CPL;    // points per chunk
    int base  = chunk * P;

    const float* tb = tables + (size_t)level * TABLE_SIZE * LEVEL_DIM;
    const v4f*   tp = (const v4f*)tb;   // entry pairs, 16B each
    v2f* wrow = (v2f*)ws + (size_t)level * N;
    float res = (float)(BASE_RES << level);
    uint32_t lv = (uint32_t)level;

    for (int i = threadIdx.x; i < P; i += BLOCK) {
        int n = base + i;
        if (n >= N) break;

        float px = __builtin_nontemporal_load(x + (size_t)n * 3 + 0);
        float py = __builtin_nontemporal_load(x + (size_t)n * 3 + 1);
        float pz = __builtin_nontemporal_load(x + (size_t)n * 3 + 2);

        px = fminf(fmaxf((px + 1.0f) * 0.5f, 0.0f), 1.0f - 1e-6f);
        py = fminf(fmaxf((py + 1.0f) * 0.5f, 0.0f), 1.0f - 1e-6f);
        pz = fminf(fmaxf((pz + 1.0f) * 0.5f, 0.0f), 1.0f - 1e-6f);

        float sx = px * res, sy = py * res, sz = pz * res;
        float fx = floorf(sx), fy = floorf(sy), fz = floorf(sz);
        float tx = sx - fx, ty = sy - fy, tz = sz - fz;
        uint32_t ix = (uint32_t)(int32_t)fx;
        uint32_t iy = (uint32_t)(int32_t)fy;
        uint32_t iz = (uint32_t)(int32_t)fz;

        uint32_t hy0 = iy * 2654435761u;
        uint32_t hy1 = (iy + 1u) * 2654435761u;
        uint32_t hz0 = iz * 805459861u;
        uint32_t hz1 = (iz + 1u) * 805459861u;
        uint32_t m00 = hy0 ^ hz0 ^ lv;
        uint32_t m01 = hy0 ^ hz1 ^ lv;
        uint32_t m10 = hy1 ^ hz0 ^ lv;
        uint32_t m11 = hy1 ^ hz1 ^ lv;

        float wx1 = tx, wx0 = 1.0f - tx;
        float wy1 = ty, wy0 = 1.0f - ty;
        float wz1 = tz, wz0 = 1.0f - tz;
        float w00 = wy0 * wz0, w01 = wy0 * wz1;
        float w10 = wy1 * wz0, w11 = wy1 * wz1;

        // a = corner x=ix (weight wx0), b = corner x=ix+1 (weight wx1),
        // each already summed over the 4 (y,z) corners.
        float ax, ay, bx, by;

        if ((ix & 1u) == 0u) {
            // even ix: hash(ix+1) == hash(ix)^1 -> shared 16B pair
            uint32_t h00 = ix ^ m00, h01 = ix ^ m01;
            uint32_t h10 = ix ^ m10, h11 = ix ^ m11;
            v4f p00 = tp[(h00 & PAIR_MASK) >> 1];
            v4f p01 = tp[(h01 & PAIR_MASK) >> 1];
            v4f p10 = tp[(h10 & PAIR_MASK) >> 1];
            v4f p11 = tp[(h11 & PAIR_MASK) >> 1];
            // bit0 of hash selects which 8B half is corner ix; other half is ix+1
            bool s00 = (h00 & 1u), s01 = (h01 & 1u);
            bool s10 = (h10 & 1u), s11 = (h11 & 1u);
            float a00x = s00 ? p00.z : p00.x, a00y = s00 ? p00.w : p00.y;
            float b00x = s00 ? p00.x : p00.z, b00y = s00 ? p00.y : p00.w;
            float a01x = s01 ? p01.z : p01.x, a01y = s01 ? p01.w : p01.y;
            float b01x = s01 ? p01.x : p01.z, b01y = s01 ? p01.y : p01.w;
            float a10x = s10 ? p10.z : p10.x, a10y = s10 ? p10.w : p10.y;
            float b10x = s10 ? p10.x : p10.z, b10y = s10 ? p10.y : p10.w;
            float a11x = s11 ? p11.z : p11.x, a11y = s11 ? p11.w : p11.y;
            float b11x = s11 ? p11.x : p11.z, b11y = s11 ? p11.y : p11.w;
            ax = a00x * w00 + a01x * w01 + a10x * w10 + a11x * w11;
            ay = a00y * w00 + a01y * w01 + a10y * w10 + a11y * w11;
            bx = b00x * w00 + b01x * w01 + b10x * w10 + b11x * w11;
            by = b00y * w00 + b01y * w01 + b10y * w10 + b11y * w11;
        } else {
            uint32_t ja = ix, jb = ix + 1u;
            v2f e00a = *(const v2f*)(tb + (size_t)(((ja ^ m00) & TABLE_MASK) * 2u));
            v2f e01a = *(const v2f*)(tb + (size_t)(((ja ^ m01) & TABLE_MASK) * 2u));
            v2f e10a = *(const v2f*)(tb + (size_t)(((ja ^ m10) & TABLE_MASK) * 2u));
            v2f e11a = *(const v2f*)(tb + (size_t)(((ja ^ m11) & TABLE_MASK) * 2u));
            v2f e00b = *(const v2f*)(tb + (size_t)(((jb ^ m00) & TABLE_MASK) * 2u));
            v2f e01b = *(const v2f*)(tb + (size_t)(((jb ^ m01) & TABLE_MASK) * 2u));
            v2f e10b = *(const v2f*)(tb + (size_t)(((jb ^ m10) & TABLE_MASK) * 2u));
            v2f e11b = *(const v2f*)(tb + (size_t)(((jb ^ m11) & TABLE_MASK) * 2u));
            ax = e00a.x * w00 + e01a.x * w01 + e10a.x * w10 + e11a.x * w11;
            ay = e00a.y * w00 + e01a.y * w01 + e10a.y * w10 + e11a.y * w11;
            bx = e00b.x * w00 + e01b.x * w01 + e10b.x * w10 + e11b.x * w11;
            by = e00b.y * w00 + e01b.y * w01 + e10b.y * w10 + e11b.y * w11;
        }

        v2f acc;
        acc.x = ax * wx0 + bx * wx1;
        acc.y = ay * wx0 + by * wx1;
        __builtin_nontemporal_store(acc, wrow + n);
    }
}

// ---------------- Phase 2: [L][N][2] -> [N][L*2] transpose ----------------
// 4 points per thread for memory-level parallelism: round-1's 2x8B-per-thread
// version ran at only ~1.1 TB/s despite full coalescing -> latency/ILP-bound
// (only 16B outstanding per thread). Now: thread t owns chunk c = t&7
// (levels 2c,2c+1) of points 4q..4q+3 (q = t>>3).
//   Loads: 4x dwordx4; per instruction the wave covers 8 rows x 256B
//          = 32 full 64B lines, 2KB fully used.
//   Stores: 4x dwordx4 NT; per instruction 8 disjoint 128B runs (full lines).
// 64B in-flight per thread both directions, 1/4 the threads of round 1.
__global__ __launch_bounds__(256) void transpose_kernel(
    const float* __restrict__ ws, float* __restrict__ out, int N)
{
    int t = blockIdx.x * blockDim.x + threadIdx.x;
    int q = t >> 3;              // quad of points 4q..4q+3
    int c = t & 7;               // 16B chunk within a point's 128B row
    int p0 = q * 4;
    if (p0 >= N) return;

    const v2f* wsp = (const v2f*)ws;
    v4f* o = (v4f*)out;          // out[p][c] = o[p*8 + c]

    if (p0 + 3 < N) {
        const v4f* ra = (const v4f*)(wsp + (size_t)(2 * c) * N);      // row 2c, point-pairs
        const v4f* rb = (const v4f*)(wsp + (size_t)(2 * c + 1) * N);  // row 2c+1
        v4f a01 = __builtin_nontemporal_load(ra + (size_t)q * 2);
        v4f a23 = __builtin_nontemporal_load(ra + (size_t)q * 2 + 1);
        v4f b01 = __builtin_nontemporal_load(rb + (size_t)q * 2);
        v4f b23 = __builtin_nontemporal_load(rb + (size_t)q * 2 + 1);

        v4f o0; o0.x = a01.x; o0.y = a01.y; o0.z = b01.x; o0.w = b01.y;
        v4f o1; o1.x = a01.z; o1.y = a01.w; o1.z = b01.z; o1.w = b01.w;
        v4f o2; o2.x = a23.x; o2.y = a23.y; o2.z = b23.x; o2.w = b23.y;
        v4f o3; o3.x = a23.z; o3.y = a23.w; o3.z = b23.z; o3.w = b23.w;
        __builtin_nontemporal_store(o0, o + (size_t)(p0 + 0) * 8 + c);
        __builtin_nontemporal_store(o1, o + (size_t)(p0 + 1) * 8 + c);
        __builtin_nontemporal_store(o2, o + (size_t)(p0 + 2) * 8 + c);
        __builtin_nontemporal_store(o3, o + (size_t)(p0 + 3) * 8 + c);
    } else {
        // tail (N not divisible by 4): scalar per-point path
        for (int p = p0; p < N; ++p) {
            v2f a = wsp[(size_t)(2 * c) * N + p];
            v2f b = wsp[(size_t)(2 * c + 1) * N + p];
            v4f t4; t4.x = a.x; t4.y = a.y; t4.z = b.x; t4.w = b.y;
            __builtin_nontemporal_store(t4, o + (size_t)p * 8 + c);
        }
    }
}

// ---------------- Fallback: point-major (round-1 kernel, passing) ----------
__device__ __forceinline__ v2f encode_point(
    const float* __restrict__ x, const float* __restrict__ tb,
    int n, float res, uint32_t lv)
{
    float px = x[(size_t)n * 3 + 0];
    float py = x[(size_t)n * 3 + 1];
    float pz = x[(size_t)n * 3 + 2];

    px = fminf(fmaxf((px + 1.0f) * 0.5f, 0.0f), 1.0f - 1e-6f);
    py = fminf(fmaxf((py + 1.0f) * 0.5f, 0.0f), 1.0f - 1e-6f);
    pz = fminf(fmaxf((pz + 1.0f) * 0.5f, 0.0f), 1.0f - 1e-6f);

    float sx = px * res, sy = py * res, sz = pz * res;
    float fx = floorf(sx), fy = floorf(sy), fz = floorf(sz);
    float tx = sx - fx, ty = sy - fy, tz = sz - fz;
    uint32_t ix = (uint32_t)(int32_t)fx;
    uint32_t iy = (uint32_t)(int32_t)fy;
    uint32_t iz = (uint32_t)(int32_t)fz;

    uint32_t hx0 = ix, hx1 = ix + 1u;
    uint32_t hy0 = iy * 2654435761u, hy1 = (iy + 1u) * 2654435761u;
    uint32_t hz0 = iz * 805459861u,  hz1 = (iz + 1u) * 805459861u;

    uint32_t idx0 = ((hx0 ^ hy0 ^ hz0 ^ lv) & TABLE_MASK) * 2u;
    uint32_t idx1 = ((hx0 ^ hy0 ^ hz1 ^ lv) & TABLE_MASK) * 2u;
    uint32_t idx2 = ((hx0 ^ hy1 ^ hz0 ^ lv) & TABLE_MASK) * 2u;
    uint32_t idx3 = ((hx0 ^ hy1 ^ hz1 ^ lv) & TABLE_MASK) * 2u;
    uint32_t idx4 = ((hx1 ^ hy0 ^ hz0 ^ lv) & TABLE_MASK) * 2u;
    uint32_t idx5 = ((hx1 ^ hy0 ^ hz1 ^ lv) & TABLE_MASK) * 2u;
    uint32_t idx6 = ((hx1 ^ hy1 ^ hz0 ^ lv) & TABLE_MASK) * 2u;
    uint32_t idx7 = ((hx1 ^ hy1 ^ hz1 ^ lv) & TABLE_MASK) * 2u;

    v2f e0 = *(const v2f*)(tb + idx0);
    v2f e1 = *(const v2f*)(tb + idx1);
    v2f e2 = *(const v2f*)(tb + idx2);
    v2f e3 = *(const v2f*)(tb + idx3);
    v2f e4 = *(const v2f*)(tb + idx4);
    v2f e5 = *(const v2f*)(tb + idx5);
    v2f e6 = *(const v2f*)(tb + idx6);
    v2f e7 = *(const v2f*)(tb + idx7);

    float wx0 = 1.0f - tx, wx1 = tx;
    float wy0 = 1.0f - ty, wy1 = ty;
    float wz0 = 1.0f - tz, wz1 = tz;

    float w0 = wx0 * wy0 * wz0;
    float w1 = wx0 * wy0 * wz1;
    float w2 = wx0 * wy1 * wz0;
    float w3 = wx0 * wy1 * wz1;
    float w4 = wx1 * wy0 * wz0;
    float w5 = wx1 * wy0 * wz1;
    float w6 = wx1 * wy1 * wz0;
    float w7 = wx1 * wy1 * wz1;

    v2f acc;
    acc.x = e0.x * w0 + e1.x * w1 + e2.x * w2 + e3.x * w3
          + e4.x * w4 + e5.x * w5 + e6.x * w6 + e7.x * w7;
    acc.y = e0.y * w0 + e1.y * w1 + e2.y * w2 + e3.y * w3
          + e4.y * w4 + e5.y * w5 + e6.y * w6 + e7.y * w7;
    return acc;
}

__global__ __launch_bounds__(256) void hashenc_fallback(
    const float* __restrict__ x, const float* __restrict__ tables,
    float* __restrict__ out, int N)
{
    int n = blockIdx.x * blockDim.x + threadIdx.x;
    if (n >= N) return;
    float* op = out + (size_t)n * (NUM_LEVELS * LEVEL_DIM);
    #pragma unroll 4
    for (int l = 0; l < NUM_LEVELS; ++l) {
        const float* tb = tables + (size_t)l * TABLE_SIZE * LEVEL_DIM;
        v2f a = encode_point(x, tb, n, (float)(BASE_RES << l), (uint32_t)l);
        *(v2f*)(op + l * 2) = a;
    }
}

extern "C" void kernel_launch(void* const* d_in, const int* in_sizes, int n_in,
                              void* d_out, int out_size, void* d_ws, size_t ws_size,
                              hipStream_t stream) {
    const float* x      = (const float*)d_in[0];
    const float* tables = (const float*)d_in[1];
    float* out          = (float*)d_out;
    int N = in_sizes[0] / 3;

    size_t ws_needed = (size_t)NUM_LEVELS * N * LEVEL_DIM * sizeof(float);
    if (ws_size >= ws_needed) {
        float* ws = (float*)d_ws;
        gather_level_kernel<<<NUM_LEVELS * CPL, BLOCK, 0, stream>>>(x, tables, ws, N);
        int tthreads = ((N + 3) / 4) * 8;   // one thread per (4-point, 16B-chunk) tile
        transpose_kernel<<<(tthreads + BLOCK - 1) / BLOCK, BLOCK, 0, stream>>>(ws, out, N);
    } else {
        hashenc_fallback<<<(N + BLOCK - 1) / BLOCK, BLOCK, 0, stream>>>(x, tables, out, N);
    }
}

// Round 4
// 362.495 us; speedup vs baseline: 1.0354x; 1.0354x over previous
//
#include <hip/hip_runtime.h>
#include <stdint.h>

#define NUM_LEVELS 16
#define LEVEL_DIM 2
#define BASE_RES 16
#define LOG2_T 19
#define TABLE_SIZE (1u << LOG2_T)
#define TABLE_MASK (TABLE_SIZE - 1u)
#define PAIR_MASK (TABLE_MASK & ~1u)   /* 0x7FFFE: 16B-aligned entry pair */

#define CPL 256      // chunk-blocks per level (8*CPL = 2048 = resident-block capacity)
#define BLOCK 256

typedef float v2f __attribute__((ext_vector_type(2)));
typedef float v4f __attribute__((ext_vector_type(4)));

// ---------------- Phase 1: level-sharded gather ----------------
// blockIdx % 8 -> XCD (dispatch round-robin). Levels 0..7 run first
// (blocks 0..2047), then 8..15; each XCD's 4MB L2 holds exactly one table.
//
// Hash-pair trick: hash = ix ^ iy*P2 ^ iz*P3 ^ lv. For EVEN ix,
// hash(ix+1) = hash(ix) ^ 1, so both x-corners sit in the same 16B-aligned
// entry pair -> one dwordx4 load covers two corners (4 line-requests/point
// instead of 8). Odd ix falls back to 8x dwordx2. Avg 6 requests/point.
//
// Empirical model (rounds 0-3): gather runs at ~0.33 line-req/cy/CU ==
// ~64 MSHRs x ~200cy L2 latency -> MSHR-latency bound. Therefore:
//   - x loads are PLAIN (round 1 measured fastest, 245.8us): NT x loads
//     are sector-granular + L3/HBM latency and clog MSHRs (round 3: +18us).
//     The ~44MB of L2 table pollution they cause is the cheaper evil.
//   - ws stores stay NT so the write stream doesn't evict L2 tables.
__global__ __launch_bounds__(256, 8) void gather_level_kernel(
    const float* __restrict__ x,
    const float* __restrict__ tables,
    float* __restrict__ ws,      // [NUM_LEVELS][N] float2, level-major
    int N)
{
    int g = blockIdx.x;
    int half  = g / (8 * CPL);          // 0 or 1
    int h     = g % (8 * CPL);
    int level = (h & 7) + 8 * half;
    int chunk = h >> 3;
    int P     = (N + CPL - 1) / CPL;    // points per chunk
    int base  = chunk * P;

    const float* tb = tables + (size_t)level * TABLE_SIZE * LEVEL_DIM;
    const v4f*   tp = (const v4f*)tb;   // entry pairs, 16B each
    v2f* wrow = (v2f*)ws + (size_t)level * N;
    float res = (float)(BASE_RES << level);
    uint32_t lv = (uint32_t)level;

    for (int i = threadIdx.x; i < P; i += BLOCK) {
        int n = base + i;
        if (n >= N) break;

        float px = x[(size_t)n * 3 + 0];
        float py = x[(size_t)n * 3 + 1];
        float pz = x[(size_t)n * 3 + 2];

        px = fminf(fmaxf((px + 1.0f) * 0.5f, 0.0f), 1.0f - 1e-6f);
        py = fminf(fmaxf((py + 1.0f) * 0.5f, 0.0f), 1.0f - 1e-6f);
        pz = fminf(fmaxf((pz + 1.0f) * 0.5f, 0.0f), 1.0f - 1e-6f);

        float sx = px * res, sy = py * res, sz = pz * res;
        float fx = floorf(sx), fy = floorf(sy), fz = floorf(sz);
        float tx = sx - fx, ty = sy - fy, tz = sz - fz;
        uint32_t ix = (uint32_t)(int32_t)fx;
        uint32_t iy = (uint32_t)(int32_t)fy;
        uint32_t iz = (uint32_t)(int32_t)fz;

        uint32_t hy0 = iy * 2654435761u;
        uint32_t hy1 = (iy + 1u) * 2654435761u;
        uint32_t hz0 = iz * 805459861u;
        uint32_t hz1 = (iz + 1u) * 805459861u;
        uint32_t m00 = hy0 ^ hz0 ^ lv;
        uint32_t m01 = hy0 ^ hz1 ^ lv;
        uint32_t m10 = hy1 ^ hz0 ^ lv;
        uint32_t m11 = hy1 ^ hz1 ^ lv;

        float wx1 = tx, wx0 = 1.0f - tx;
        float wy1 = ty, wy0 = 1.0f - ty;
        float wz1 = tz, wz0 = 1.0f - tz;
        float w00 = wy0 * wz0, w01 = wy0 * wz1;
        float w10 = wy1 * wz0, w11 = wy1 * wz1;

        // a = corner x=ix (weight wx0), b = corner x=ix+1 (weight wx1),
        // each already summed over the 4 (y,z) corners.
        float ax, ay, bx, by;

        if ((ix & 1u) == 0u) {
            // even ix: hash(ix+1) == hash(ix)^1 -> shared 16B pair
            uint32_t h00 = ix ^ m00, h01 = ix ^ m01;
            uint32_t h10 = ix ^ m10, h11 = ix ^ m11;
            v4f p00 = tp[(h00 & PAIR_MASK) >> 1];
            v4f p01 = tp[(h01 & PAIR_MASK) >> 1];
            v4f p10 = tp[(h10 & PAIR_MASK) >> 1];
            v4f p11 = tp[(h11 & PAIR_MASK) >> 1];
            // bit0 of hash selects which 8B half is corner ix; other half is ix+1
            bool s00 = (h00 & 1u), s01 = (h01 & 1u);
            bool s10 = (h10 & 1u), s11 = (h11 & 1u);
            float a00x = s00 ? p00.z : p00.x, a00y = s00 ? p00.w : p00.y;
            float b00x = s00 ? p00.x : p00.z, b00y = s00 ? p00.y : p00.w;
            float a01x = s01 ? p01.z : p01.x, a01y = s01 ? p01.w : p01.y;
            float b01x = s01 ? p01.x : p01.z, b01y = s01 ? p01.y : p01.w;
            float a10x = s10 ? p10.z : p10.x, a10y = s10 ? p10.w : p10.y;
            float b10x = s10 ? p10.x : p10.z, b10y = s10 ? p10.y : p10.w;
            float a11x = s11 ? p11.z : p11.x, a11y = s11 ? p11.w : p11.y;
            float b11x = s11 ? p11.x : p11.z, b11y = s11 ? p11.y : p11.w;
            ax = a00x * w00 + a01x * w01 + a10x * w10 + a11x * w11;
            ay = a00y * w00 + a01y * w01 + a10y * w10 + a11y * w11;
            bx = b00x * w00 + b01x * w01 + b10x * w10 + b11x * w11;
            by = b00y * w00 + b01y * w01 + b10y * w10 + b11y * w11;
        } else {
            uint32_t ja = ix, jb = ix + 1u;
            v2f e00a = *(const v2f*)(tb + (size_t)(((ja ^ m00) & TABLE_MASK) * 2u));
            v2f e01a = *(const v2f*)(tb + (size_t)(((ja ^ m01) & TABLE_MASK) * 2u));
            v2f e10a = *(const v2f*)(tb + (size_t)(((ja ^ m10) & TABLE_MASK) * 2u));
            v2f e11a = *(const v2f*)(tb + (size_t)(((ja ^ m11) & TABLE_MASK) * 2u));
            v2f e00b = *(const v2f*)(tb + (size_t)(((jb ^ m00) & TABLE_MASK) * 2u));
            v2f e01b = *(const v2f*)(tb + (size_t)(((jb ^ m01) & TABLE_MASK) * 2u));
            v2f e10b = *(const v2f*)(tb + (size_t)(((jb ^ m10) & TABLE_MASK) * 2u));
            v2f e11b = *(const v2f*)(tb + (size_t)(((jb ^ m11) & TABLE_MASK) * 2u));
            ax = e00a.x * w00 + e01a.x * w01 + e10a.x * w10 + e11a.x * w11;
            ay = e00a.y * w00 + e01a.y * w01 + e10a.y * w10 + e11a.y * w11;
            bx = e00b.x * w00 + e01b.x * w01 + e10b.x * w10 + e11b.x * w11;
            by = e00b.y * w00 + e01b.y * w01 + e10b.y * w10 + e11b.y * w11;
        }

        v2f acc;
        acc.x = ax * wx0 + bx * wx1;
        acc.y = ay * wx0 + by * wx1;
        __builtin_nontemporal_store(acc, wrow + n);
    }
}

// ---------------- Phase 2: [L][N][2] -> [N][L*2] transpose ----------------
// PLAIN loads and stores on purpose. Three NT variants (scalar, full-line
// 1-pt, 4-pt MLP) all measured ~111us == 1.1 TB/s: NT no-allocate loads are
// sector-granular (a wave's 1KB of 16B loads = 64 sector requests instead of
// 16 line fills, 4x the MSHR slots) at HBM latency (NT stores wrote ws
// through to HBM). Plain loads fill 64B lines into L1/L2; plain stores merge
// in L2 before writeback. Thread t owns chunk c = t&7 (levels 2c,2c+1) of
// points 4q..4q+3 (q = t>>3): loads are fully coalesced (wave covers 8 rows
// x 256B = 32 full lines per instr), stores cover 8 x 128B full-line runs.
__global__ __launch_bounds__(256) void transpose_kernel(
    const float* __restrict__ ws, float* __restrict__ out, int N)
{
    int t = blockIdx.x * blockDim.x + threadIdx.x;
    int q = t >> 3;              // quad of points 4q..4q+3
    int c = t & 7;               // 16B chunk within a point's 128B row
    int p0 = q * 4;
    if (p0 >= N) return;

    const v2f* wsp = (const v2f*)ws;
    v4f* o = (v4f*)out;          // out[p][c] = o[p*8 + c]

    if (p0 + 3 < N) {
        const v4f* ra = (const v4f*)(wsp + (size_t)(2 * c) * N);      // row 2c, point-pairs
        const v4f* rb = (const v4f*)(wsp + (size_t)(2 * c + 1) * N);  // row 2c+1
        v4f a01 = ra[(size_t)q * 2];
        v4f a23 = ra[(size_t)q * 2 + 1];
        v4f b01 = rb[(size_t)q * 2];
        v4f b23 = rb[(size_t)q * 2 + 1];

        v4f o0; o0.x = a01.x; o0.y = a01.y; o0.z = b01.x; o0.w = b01.y;
        v4f o1; o1.x = a01.z; o1.y = a01.w; o1.z = b01.z; o1.w = b01.w;
        v4f o2; o2.x = a23.x; o2.y = a23.y; o2.z = b23.x; o2.w = b23.y;
        v4f o3; o3.x = a23.z; o3.y = a23.w; o3.z = b23.z; o3.w = b23.w;
        o[(size_t)(p0 + 0) * 8 + c] = o0;
        o[(size_t)(p0 + 1) * 8 + c] = o1;
        o[(size_t)(p0 + 2) * 8 + c] = o2;
        o[(size_t)(p0 + 3) * 8 + c] = o3;
    } else {
        // tail (N not divisible by 4): scalar per-point path
        for (int p = p0; p < N; ++p) {
            v2f a = wsp[(size_t)(2 * c) * N + p];
            v2f b = wsp[(size_t)(2 * c + 1) * N + p];
            v4f t4; t4.x = a.x; t4.y = a.y; t4.z = b.x; t4.w = b.y;
            o[(size_t)p * 8 + c] = t4;
        }
    }
}

// ---------------- Fallback: point-major (round-1 kernel, passing) ----------
__device__ __forceinline__ v2f encode_point(
    const float* __restrict__ x, const float* __restrict__ tb,
    int n, float res, uint32_t lv)
{
    float px = x[(size_t)n * 3 + 0];
    float py = x[(size_t)n * 3 + 1];
    float pz = x[(size_t)n * 3 + 2];

    px = fminf(fmaxf((px + 1.0f) * 0.5f, 0.0f), 1.0f - 1e-6f);
    py = fminf(fmaxf((py + 1.0f) * 0.5f, 0.0f), 1.0f - 1e-6f);
    pz = fminf(fmaxf((pz + 1.0f) * 0.5f, 0.0f), 1.0f - 1e-6f);

    float sx = px * res, sy = py * res, sz = pz * res;
    float fx = floorf(sx), fy = floorf(sy), fz = floorf(sz);
    float tx = sx - fx, ty = sy - fy, tz = sz - fz;
    uint32_t ix = (uint32_t)(int32_t)fx;
    uint32_t iy = (uint32_t)(int32_t)fy;
    uint32_t iz = (uint32_t)(int32_t)fz;

    uint32_t hx0 = ix, hx1 = ix + 1u;
    uint32_t hy0 = iy * 2654435761u, hy1 = (iy + 1u) * 2654435761u;
    uint32_t hz0 = iz * 805459861u,  hz1 = (iz + 1u) * 805459861u;

    uint32_t idx0 = ((hx0 ^ hy0 ^ hz0 ^ lv) & TABLE_MASK) * 2u;
    uint32_t idx1 = ((hx0 ^ hy0 ^ hz1 ^ lv) & TABLE_MASK) * 2u;
    uint32_t idx2 = ((hx0 ^ hy1 ^ hz0 ^ lv) & TABLE_MASK) * 2u;
    uint32_t idx3 = ((hx0 ^ hy1 ^ hz1 ^ lv) & TABLE_MASK) * 2u;
    uint32_t idx4 = ((hx1 ^ hy0 ^ hz0 ^ lv) & TABLE_MASK) * 2u;
    uint32_t idx5 = ((hx1 ^ hy0 ^ hz1 ^ lv) & TABLE_MASK) * 2u;
    uint32_t idx6 = ((hx1 ^ hy1 ^ hz0 ^ lv) & TABLE_MASK) * 2u;
    uint32_t idx7 = ((hx1 ^ hy1 ^ hz1 ^ lv) & TABLE_MASK) * 2u;

    v2f e0 = *(const v2f*)(tb + idx0);
    v2f e1 = *(const v2f*)(tb + idx1);
    v2f e2 = *(const v2f*)(tb + idx2);
    v2f e3 = *(const v2f*)(tb + idx3);
    v2f e4 = *(const v2f*)(tb + idx4);
    v2f e5 = *(const v2f*)(tb + idx5);
    v2f e6 = *(const v2f*)(tb + idx6);
    v2f e7 = *(const v2f*)(tb + idx7);

    float wx0 = 1.0f - tx, wx1 = tx;
    float wy0 = 1.0f - ty, wy1 = ty;
    float wz0 = 1.0f - tz, wz1 = tz;

    float w0 = wx0 * wy0 * wz0;
    float w1 = wx0 * wy0 * wz1;
    float w2 = wx0 * wy1 * wz0;
    float w3 = wx0 * wy1 * wz1;
    float w4 = wx1 * wy0 * wz0;
    float w5 = wx1 * wy0 * wz1;
    float w6 = wx1 * wy1 * wz0;
    float w7 = wx1 * wy1 * wz1;

    v2f acc;
    acc.x = e0.x * w0 + e1.x * w1 + e2.x * w2 + e3.x * w3
          + e4.x * w4 + e5.x * w5 + e6.x * w6 + e7.x * w7;
    acc.y = e0.y * w0 + e1.y * w1 + e2.y * w2 + e3.y * w3
          + e4.y * w4 + e5.y * w5 + e6.y * w6 + e7.y * w7;
    return acc;
}

__global__ __launch_bounds__(256) void hashenc_fallback(
    const float* __restrict__ x, const float* __restrict__ tables,
    float* __restrict__ out, int N)
{
    int n = blockIdx.x * blockDim.x + threadIdx.x;
    if (n >= N) return;
    float* op = out + (size_t)n * (NUM_LEVELS * LEVEL_DIM);
    #pragma unroll 4
    for (int l = 0; l < NUM_LEVELS; ++l) {
        const float* tb = tables + (size_t)l * TABLE_SIZE * LEVEL_DIM;
        v2f a = encode_point(x, tb, n, (float)(BASE_RES << l), (uint32_t)l);
        *(v2f*)(op + l * 2) = a;
    }
}

extern "C" void kernel_launch(void* const* d_in, const int* in_sizes, int n_in,
                              void* d_out, int out_size, void* d_ws, size_t ws_size,
                              hipStream_t stream) {
    const float* x      = (const float*)d_in[0];
    const float* tables = (const float*)d_in[1];
    float* out          = (float*)d_out;
    int N = in_sizes[0] / 3;

    size_t ws_needed = (size_t)NUM_LEVELS * N * LEVEL_DIM * sizeof(float);
    if (ws_size >= ws_needed) {
        float* ws = (float*)d_ws;
        gather_level_kernel<<<NUM_LEVELS * CPL, BLOCK, 0, stream>>>(x, tables, ws, N);
        int tthreads = ((N + 3) / 4) * 8;   // one thread per (4-point, 16B-chunk) tile
        transpose_kernel<<<(tthreads + BLOCK - 1) / BLOCK, BLOCK, 0, stream>>>(ws, out, N);
    } else {
        hashenc_fallback<<<(N + BLOCK - 1) / BLOCK, BLOCK, 0, stream>>>(x, tables, out, N);
    }
}

// Round 5
// 361.251 us; speedup vs baseline: 1.0389x; 1.0034x over previous
//
#include <hip/hip_runtime.h>
#include <stdint.h>

#define NUM_LEVELS 16
#define LEVEL_DIM 2
#define BASE_RES 16
#define LOG2_T 19
#define TABLE_SIZE (1u << LOG2_T)
#define TABLE_MASK (TABLE_SIZE - 1u)
#define PAIR_MASK (TABLE_MASK & ~1u)   /* 0x7FFFE: 16B-aligned entry pair */

#define CPL 256      // chunk-blocks per level
#define BLOCK 256
#define CHUNK 2048   // points per chunk (LDS x-tile capacity)

typedef float v2f __attribute__((ext_vector_type(2)));
typedef float v4f __attribute__((ext_vector_type(4)));

// ---------------- Phase 1: level-sharded gather ----------------
// blockIdx % 8 -> XCD (dispatch round-robin). Levels 0..7 run first
// (blocks 0..2047), then 8..15; each XCD's 4MB L2 holds exactly one table.
//
// Hash-pair trick: hash = ix ^ iy*P2 ^ iz*P3 ^ lv. For EVEN ix,
// hash(ix+1) = hash(ix) ^ 1, so both x-corners sit in the same 16B-aligned
// entry pair -> one dwordx4 load covers two corners. Avg 6 line-req/point.
//
// Empirical model (rounds 0-4): gather time scales ~linearly with TOTAL
// VMEM lane-addresses (~0.55 addr/cy/CU effective): r0 100.7M addrs=317us,
// r1/r4 83.9M=246us. Table gathers are irreducible (6/pt); the 3 scalar
// x loads/pt (25.2M addrs, 30% of budget) are not: this version stages the
// block's 24KB x-chunk into LDS once (NT v4f, 1536 lane-addrs/block vs
// 6144) and reads coords from the LDS pipe (free of the TCP/TA limit;
// stride-3 words -> all 32 banks, conflict-free). NT staging also keeps the
// x stream out of L2 (r1 measured +44MB table refetch from plain scalar x).
__global__ __launch_bounds__(256, 6) void gather_level_kernel(
    const float* __restrict__ x,
    const float* __restrict__ tables,
    float* __restrict__ ws,      // [NUM_LEVELS][N] float2, level-major
    int N)
{
    __shared__ __align__(16) float xs[CHUNK * 3];   // 24KB -> 6 blocks/CU

    int g = blockIdx.x;
    int half  = g / (8 * CPL);          // 0 or 1
    int h     = g % (8 * CPL);
    int level = (h & 7) + 8 * half;
    int chunk = h >> 3;
    int P     = (N + CPL - 1) / CPL;    // points per chunk (launcher ensures <= CHUNK, %4==0)
    int base  = chunk * P;
    int cnt   = N - base; if (cnt > P) cnt = P; if (cnt < 0) cnt = 0;

    // ---- stage x[base .. base+cnt) into LDS, coalesced NT v4f ----
    {
        const float* xg = x + (size_t)base * 3;
        int nfl = cnt * 3;
        int nv4 = nfl >> 2;             // whole v4f's (xg 16B-aligned: base%4==0)
        const v4f* xg4 = (const v4f*)xg;
        for (int j = threadIdx.x; j < nv4; j += BLOCK) {
            v4f v = __builtin_nontemporal_load(xg4 + j);
            *(v4f*)(xs + 4 * j) = v;
        }
        for (int f = (nv4 << 2) + threadIdx.x; f < nfl; f += BLOCK)
            xs[f] = __builtin_nontemporal_load(xg + f);
    }
    __syncthreads();

    const float* tb = tables + (size_t)level * TABLE_SIZE * LEVEL_DIM;
    const v4f*   tp = (const v4f*)tb;   // entry pairs, 16B each
    v2f* wrow = (v2f*)ws + (size_t)level * N;
    float res = (float)(BASE_RES << level);
    uint32_t lv = (uint32_t)level;

    for (int i = threadIdx.x; i < cnt; i += BLOCK) {
        int n = base + i;

        float px = xs[i * 3 + 0];
        float py = xs[i * 3 + 1];
        float pz = xs[i * 3 + 2];

        px = fminf(fmaxf((px + 1.0f) * 0.5f, 0.0f), 1.0f - 1e-6f);
        py = fminf(fmaxf((py + 1.0f) * 0.5f, 0.0f), 1.0f - 1e-6f);
        pz = fminf(fmaxf((pz + 1.0f) * 0.5f, 0.0f), 1.0f - 1e-6f);

        float sx = px * res, sy = py * res, sz = pz * res;
        float fx = floorf(sx), fy = floorf(sy), fz = floorf(sz);
        float tx = sx - fx, ty = sy - fy, tz = sz - fz;
        uint32_t ix = (uint32_t)(int32_t)fx;
        uint32_t iy = (uint32_t)(int32_t)fy;
        uint32_t iz = (uint32_t)(int32_t)fz;

        uint32_t hy0 = iy * 2654435761u;
        uint32_t hy1 = (iy + 1u) * 2654435761u;
        uint32_t hz0 = iz * 805459861u;
        uint32_t hz1 = (iz + 1u) * 805459861u;
        uint32_t m00 = hy0 ^ hz0 ^ lv;
        uint32_t m01 = hy0 ^ hz1 ^ lv;
        uint32_t m10 = hy1 ^ hz0 ^ lv;
        uint32_t m11 = hy1 ^ hz1 ^ lv;

        float wx1 = tx, wx0 = 1.0f - tx;
        float wy1 = ty, wy0 = 1.0f - ty;
        float wz1 = tz, wz0 = 1.0f - tz;
        float w00 = wy0 * wz0, w01 = wy0 * wz1;
        float w10 = wy1 * wz0, w11 = wy1 * wz1;

        // a = corner x=ix (weight wx0), b = corner x=ix+1 (weight wx1),
        // each already summed over the 4 (y,z) corners.
        float ax, ay, bx, by;

        if ((ix & 1u) == 0u) {
            // even ix: hash(ix+1) == hash(ix)^1 -> shared 16B pair
            uint32_t h00 = ix ^ m00, h01 = ix ^ m01;
            uint32_t h10 = ix ^ m10, h11 = ix ^ m11;
            v4f p00 = tp[(h00 & PAIR_MASK) >> 1];
            v4f p01 = tp[(h01 & PAIR_MASK) >> 1];
            v4f p10 = tp[(h10 & PAIR_MASK) >> 1];
            v4f p11 = tp[(h11 & PAIR_MASK) >> 1];
            // bit0 of hash selects which 8B half is corner ix; other half is ix+1
            bool s00 = (h00 & 1u), s01 = (h01 & 1u);
            bool s10 = (h10 & 1u), s11 = (h11 & 1u);
            float a00x = s00 ? p00.z : p00.x, a00y = s00 ? p00.w : p00.y;
            float b00x = s00 ? p00.x : p00.z, b00y = s00 ? p00.y : p00.w;
            float a01x = s01 ? p01.z : p01.x, a01y = s01 ? p01.w : p01.y;
            float b01x = s01 ? p01.x : p01.z, b01y = s01 ? p01.y : p01.w;
            float a10x = s10 ? p10.z : p10.x, a10y = s10 ? p10.w : p10.y;
            float b10x = s10 ? p10.x : p10.z, b10y = s10 ? p10.y : p10.w;
            float a11x = s11 ? p11.z : p11.x, a11y = s11 ? p11.w : p11.y;
            float b11x = s11 ? p11.x : p11.z, b11y = s11 ? p11.y : p11.w;
            ax = a00x * w00 + a01x * w01 + a10x * w10 + a11x * w11;
            ay = a00y * w00 + a01y * w01 + a10y * w10 + a11y * w11;
            bx = b00x * w00 + b01x * w01 + b10x * w10 + b11x * w11;
            by = b00y * w00 + b01y * w01 + b10y * w10 + b11y * w11;
        } else {
            uint32_t ja = ix, jb = ix + 1u;
            v2f e00a = *(const v2f*)(tb + (size_t)(((ja ^ m00) & TABLE_MASK) * 2u));
            v2f e01a = *(const v2f*)(tb + (size_t)(((ja ^ m01) & TABLE_MASK) * 2u));
            v2f e10a = *(const v2f*)(tb + (size_t)(((ja ^ m10) & TABLE_MASK) * 2u));
            v2f e11a = *(const v2f*)(tb + (size_t)(((ja ^ m11) & TABLE_MASK) * 2u));
            v2f e00b = *(const v2f*)(tb + (size_t)(((jb ^ m00) & TABLE_MASK) * 2u));
            v2f e01b = *(const v2f*)(tb + (size_t)(((jb ^ m01) & TABLE_MASK) * 2u));
            v2f e10b = *(const v2f*)(tb + (size_t)(((jb ^ m10) & TABLE_MASK) * 2u));
            v2f e11b = *(const v2f*)(tb + (size_t)(((jb ^ m11) & TABLE_MASK) * 2u));
            ax = e00a.x * w00 + e01a.x * w01 + e10a.x * w10 + e11a.x * w11;
            ay = e00a.y * w00 + e01a.y * w01 + e10a.y * w10 + e11a.y * w11;
            bx = e00b.x * w00 + e01b.x * w01 + e10b.x * w10 + e11b.x * w11;
            by = e00b.y * w00 + e01b.y * w01 + e10b.y * w10 + e11b.y * w11;
        }

        v2f acc;
        acc.x = ax * wx0 + bx * wx1;
        acc.y = ay * wx0 + by * wx1;
        __builtin_nontemporal_store(acc, wrow + n);
    }
}

// ---------------- Phase 2: [L][N][2] -> [N][L*2] transpose ----------------
// CONTROL: byte-identical to round 4. Measured invariant (~114us incl.
// launch overhead) across 4 structurally different implementations; left
// untouched so the gather change is a clean A/B.
__global__ __launch_bounds__(256) void transpose_kernel(
    const float* __restrict__ ws, float* __restrict__ out, int N)
{
    int t = blockIdx.x * blockDim.x + threadIdx.x;
    int q = t >> 3;              // quad of points 4q..4q+3
    int c = t & 7;               // 16B chunk within a point's 128B row
    int p0 = q * 4;
    if (p0 >= N) return;

    const v2f* wsp = (const v2f*)ws;
    v4f* o = (v4f*)out;          // out[p][c] = o[p*8 + c]

    if (p0 + 3 < N) {
        const v4f* ra = (const v4f*)(wsp + (size_t)(2 * c) * N);      // row 2c, point-pairs
        const v4f* rb = (const v4f*)(wsp + (size_t)(2 * c + 1) * N);  // row 2c+1
        v4f a01 = ra[(size_t)q * 2];
        v4f a23 = ra[(size_t)q * 2 + 1];
        v4f b01 = rb[(size_t)q * 2];
        v4f b23 = rb[(size_t)q * 2 + 1];

        v4f o0; o0.x = a01.x; o0.y = a01.y; o0.z = b01.x; o0.w = b01.y;
        v4f o1; o1.x = a01.z; o1.y = a01.w; o1.z = b01.z; o1.w = b01.w;
        v4f o2; o2.x = a23.x; o2.y = a23.y; o2.z = b23.x; o2.w = b23.y;
        v4f o3; o3.x = a23.z; o3.y = a23.w; o3.z = b23.z; o3.w = b23.w;
        o[(size_t)(p0 + 0) * 8 + c] = o0;
        o[(size_t)(p0 + 1) * 8 + c] = o1;
        o[(size_t)(p0 + 2) * 8 + c] = o2;
        o[(size_t)(p0 + 3) * 8 + c] = o3;
    } else {
        // tail (N not divisible by 4): scalar per-point path
        for (int p = p0; p < N; ++p) {
            v2f a = wsp[(size_t)(2 * c) * N + p];
            v2f b = wsp[(size_t)(2 * c + 1) * N + p];
            v4f t4; t4.x = a.x; t4.y = a.y; t4.z = b.x; t4.w = b.y;
            o[(size_t)p * 8 + c] = t4;
        }
    }
}

// ---------------- Fallback: point-major (round-1 kernel, passing) ----------
__device__ __forceinline__ v2f encode_point(
    const float* __restrict__ x, const float* __restrict__ tb,
    int n, float res, uint32_t lv)
{
    float px = x[(size_t)n * 3 + 0];
    float py = x[(size_t)n * 3 + 1];
    float pz = x[(size_t)n * 3 + 2];

    px = fminf(fmaxf((px + 1.0f) * 0.5f, 0.0f), 1.0f - 1e-6f);
    py = fminf(fmaxf((py + 1.0f) * 0.5f, 0.0f), 1.0f - 1e-6f);
    pz = fminf(fmaxf((pz + 1.0f) * 0.5f, 0.0f), 1.0f - 1e-6f);

    float sx = px * res, sy = py * res, sz = pz * res;
    float fx = floorf(sx), fy = floorf(sy), fz = floorf(sz);
    float tx = sx - fx, ty = sy - fy, tz = sz - fz;
    uint32_t ix = (uint32_t)(int32_t)fx;
    uint32_t iy = (uint32_t)(int32_t)fy;
    uint32_t iz = (uint32_t)(int32_t)fz;

    uint32_t hx0 = ix, hx1 = ix + 1u;
    uint32_t hy0 = iy * 2654435761u, hy1 = (iy + 1u) * 2654435761u;
    uint32_t hz0 = iz * 805459861u,  hz1 = (iz + 1u) * 805459861u;

    uint32_t idx0 = ((hx0 ^ hy0 ^ hz0 ^ lv) & TABLE_MASK) * 2u;
    uint32_t idx1 = ((hx0 ^ hy0 ^ hz1 ^ lv) & TABLE_MASK) * 2u;
    uint32_t idx2 = ((hx0 ^ hy1 ^ hz0 ^ lv) & TABLE_MASK) * 2u;
    uint32_t idx3 = ((hx0 ^ hy1 ^ hz1 ^ lv) & TABLE_MASK) * 2u;
    uint32_t idx4 = ((hx1 ^ hy0 ^ hz0 ^ lv) & TABLE_MASK) * 2u;
    uint32_t idx5 = ((hx1 ^ hy0 ^ hz1 ^ lv) & TABLE_MASK) * 2u;
    uint32_t idx6 = ((hx1 ^ hy1 ^ hz0 ^ lv) & TABLE_MASK) * 2u;
    uint32_t idx7 = ((hx1 ^ hy1 ^ hz1 ^ lv) & TABLE_MASK) * 2u;

    v2f e0 = *(const v2f*)(tb + idx0);
    v2f e1 = *(const v2f*)(tb + idx1);
    v2f e2 = *(const v2f*)(tb + idx2);
    v2f e3 = *(const v2f*)(tb + idx3);
    v2f e4 = *(const v2f*)(tb + idx4);
    v2f e5 = *(const v2f*)(tb + idx5);
    v2f e6 = *(const v2f*)(tb + idx6);
    v2f e7 = *(const v2f*)(tb + idx7);

    float wx0 = 1.0f - tx, wx1 = tx;
    float wy0 = 1.0f - ty, wy1 = ty;
    float wz0 = 1.0f - tz, wz1 = tz;

    float w0 = wx0 * wy0 * wz0;
    float w1 = wx0 * wy0 * wz1;
    float w2 = wx0 * wy1 * wz0;
    float w3 = wx0 * wy1 * wz1;
    float w4 = wx1 * wy0 * wz0;
    float w5 = wx1 * wy0 * wz1;
    float w6 = wx1 * wy1 * wz0;
    float w7 = wx1 * wy1 * wz1;

    v2f acc;
    acc.x = e0.x * w0 + e1.x * w1 + e2.x * w2 + e3.x * w3
          + e4.x * w4 + e5.x * w5 + e6.x * w6 + e7.x * w7;
    acc.y = e0.y * w0 + e1.y * w1 + e2.y * w2 + e3.y * w3
          + e4.y * w4 + e5.y * w5 + e6.y * w6 + e7.y * w7;
    return acc;
}

__global__ __launch_bounds__(256) void hashenc_fallback(
    const float* __restrict__ x, const float* __restrict__ tables,
    float* __restrict__ out, int N)
{
    int n = blockIdx.x * blockDim.x + threadIdx.x;
    if (n >= N) return;
    float* op = out + (size_t)n * (NUM_LEVELS * LEVEL_DIM);
    #pragma unroll 4
    for (int l = 0; l < NUM_LEVELS; ++l) {
        const float* tb = tables + (size_t)l * TABLE_SIZE * LEVEL_DIM;
        v2f a = encode_point(x, tb, n, (float)(BASE_RES << l), (uint32_t)l);
        *(v2f*)(op + l * 2) = a;
    }
}

extern "C" void kernel_launch(void* const* d_in, const int* in_sizes, int n_in,
                              void* d_out, int out_size, void* d_ws, size_t ws_size,
                              hipStream_t stream) {
    const float* x      = (const float*)d_in[0];
    const float* tables = (const float*)d_in[1];
    float* out          = (float*)d_out;
    int N = in_sizes[0] / 3;

    size_t ws_needed = (size_t)NUM_LEVELS * N * LEVEL_DIM * sizeof(float);
    int P = (N + CPL - 1) / CPL;
    // gather kernel requires: chunk fits LDS tile, P%4==0 (v4f-aligned x tile
    // base: base*3*4B % 16 == 0), ws large enough.
    if (ws_size >= ws_needed && P <= CHUNK && (P & 3) == 0) {
        float* ws = (float*)d_ws;
        gather_level_kernel<<<NUM_LEVELS * CPL, BLOCK, 0, stream>>>(x, tables, ws, N);
        int tthreads = ((N + 3) / 4) * 8;   // one thread per (4-point, 16B-chunk) tile
        transpose_kernel<<<(tthreads + BLOCK - 1) / BLOCK, BLOCK, 0, stream>>>(ws, out, N);
    } else {
        hashenc_fallback<<<(N + BLOCK - 1) / BLOCK, BLOCK, 0, stream>>>(x, tables, out, N);
    }
}